// Round 13
// baseline (385.679 us; speedup 1.0000x reference)
//
#include <hip/hip_runtime.h>

typedef unsigned short u16;
typedef __bf16 bf16x8 __attribute__((ext_vector_type(8)));
typedef float  f32x4  __attribute__((ext_vector_type(4)));

#define SEQ 2048

__device__ __forceinline__ float bf2f(u16 u) {
    union { unsigned int i; float f; } c;
    c.i = ((unsigned int)u) << 16;
    return c.f;
}
__device__ __forceinline__ u16 f2bf(float f) {
    union { float f; unsigned int i; } c;
    c.f = f;
    unsigned int u = c.i;
    u += 0x7FFFu + ((u >> 16) & 1u);   // round-to-nearest-even
    return (u16)(u >> 16);
}

// async global->LDS, 16B per lane; lds dest = wave-uniform base + lane*16
__device__ __forceinline__ void gl_lds16(const u16* g, u16* l) {
    __builtin_amdgcn_global_load_lds(
        (const __attribute__((address_space(1))) unsigned int*)(g),
        (__attribute__((address_space(3))) unsigned int*)(l), 16, 0, 0);
}

__device__ __forceinline__ void cvt4(const float* s, u16* d) {
    float4 v = *(const float4*)s;
    ushort4 o;
    o.x = f2bf(v.x); o.y = f2bf(v.y); o.z = f2bf(v.z); o.w = f2bf(v.w);
    *(ushort4*)d = o;
}

// ---------------------------------------------------------------- fused prep
// Converts x/wq/wk/wv (+ wo when wob != nullptr) to bf16 and packs biases.
__global__ void prep(const float* __restrict__ x,
                     const float* __restrict__ wq, const float* __restrict__ wk,
                     const float* __restrict__ wv, const float* __restrict__ wo,
                     const float* __restrict__ bq, const float* __restrict__ bk,
                     const float* __restrict__ bv,
                     u16* __restrict__ xb, u16* __restrict__ wqkvb,
                     float* __restrict__ biasb, u16* __restrict__ wob)
{
    const int E0 = 2097152;            // x float4s
    const int E1 = E0 + 1048576;       // wq
    const int E2 = E1 + 262144;        // wk
    const int E3 = E2 + 262144;        // wv
    const int E4 = E3 + 768;           // bias float4s
    const int EN = wob ? (E4 + 1048576) : E4;   // + wo float4s (fused path)
    int i = blockIdx.x * blockDim.x + threadIdx.x;
    int stride = gridDim.x * blockDim.x;
    for (; i < EN; i += stride) {
        if (i < E0)      cvt4(x  + (size_t)i * 4,        xb    + (size_t)i * 4);
        else if (i < E1) cvt4(wq + (size_t)(i - E0) * 4, wqkvb + (size_t)(i - E0) * 4);
        else if (i < E2) cvt4(wk + (size_t)(i - E1) * 4, wqkvb + 4194304 + (size_t)(i - E1) * 4);
        else if (i < E3) cvt4(wv + (size_t)(i - E2) * 4, wqkvb + 5242880 + (size_t)(i - E2) * 4);
        else if (i < E4) {
            int j = i - E3;            // 0..767
            const float* src = (j < 512) ? (bq + j * 4)
                             : (j < 640) ? (bk + (j - 512) * 4)
                                         : (bv + (j - 640) * 4);
            *(float4*)&biasb[j * 4] = *(const float4*)src;
        } else {
            int j = i - E4;            // 0..1048575
            cvt4(wo + (size_t)j * 4, wob + (size_t)j * 4);
        }
    }
}

__global__ void cvt_f32_bf16(const float* __restrict__ in, u16* __restrict__ out, int n4) {
    int i = blockIdx.x * blockDim.x + threadIdx.x;
    int stride = gridDim.x * blockDim.x;
    for (; i < n4; i += stride) cvt4(in + (size_t)i * 4, out + (size_t)i * 4);
}

// ---------------------------------------------------------------- GEMM C = A*B^T + bias (128^2, BK=32, m97 pattern)
// PROVEN kernel. Natural dim3 grid (r8/r10 lessons: no XCD remap, no T2/BK64).
// MODE 0: full-K, C fp32 store.   MODE 1: full-K, qkv split-write.
// MODE 2 (r13): split-K over blockIdx.z (grid z=2). Each half K=1024;
//   epilogue atomicAdd fp32 into pre-zeroed C; bias added by bz==0 only.
//   Raises gemm2 occupancy 2->4 blocks/CU (the quantified deficit: 430 vs
//   603 TF on identical code at 3/CU). Parameter-class change, sync untouched.
template<int MODE>
__global__ __launch_bounds__(256) void gemm_bt(
    const u16* __restrict__ A, const u16* __restrict__ B,
    const float* __restrict__ bias, float* __restrict__ C,
    u16* __restrict__ qb, u16* __restrict__ kb, u16* __restrict__ vt,
    int M, int N, int K)
{
    __shared__ __align__(16) u16 lA[128 * 32];
    __shared__ __align__(16) u16 lB[128 * 32];
    const int tid   = threadIdx.x;
    const int lane  = tid & 63;
    const int wave  = tid >> 6;
    const int waveM = (wave >> 1) * 64;
    const int waveN = (wave & 1) * 64;
    const int bm = blockIdx.x * 128;
    const int bn = blockIdx.y * 128;
    const int lrow = lane & 15;
    const int koff = (lane >> 4) * 8;

    const int kbeg = (MODE == 2) ? (int)blockIdx.z * (K >> 1) : 0;
    const int kend = (MODE == 2) ? kbeg + (K >> 1) : K;

    f32x4 acc[4][4] = {};

    for (int k0 = kbeg; k0 < kend; k0 += 32) {
        __syncthreads();
#pragma unroll
        for (int p = 0; p < 2; ++p) {
            int idx = p * 256 + tid;    // 0..511
            int row = idx >> 2;         // 0..127
            int ch  = idx & 3;          // 16B chunk
            gl_lds16(&A[(size_t)(bm + row) * K + k0 + ch * 8], &lA[(p * 256 + wave * 64) * 8]);
            gl_lds16(&B[(size_t)(bn + row) * K + k0 + ch * 8], &lB[(p * 256 + wave * 64) * 8]);
        }
        __syncthreads();

        bf16x8 af[4], bfr[4];
#pragma unroll
        for (int i = 0; i < 4; ++i)
            af[i] = *(const bf16x8*)&lA[(waveM + i * 16 + lrow) * 32 + koff];
#pragma unroll
        for (int j = 0; j < 4; ++j)
            bfr[j] = *(const bf16x8*)&lB[(waveN + j * 16 + lrow) * 32 + koff];
#pragma unroll
        for (int i = 0; i < 4; ++i)
#pragma unroll
            for (int j = 0; j < 4; ++j)
                acc[i][j] = __builtin_amdgcn_mfma_f32_16x16x32_bf16(
                    af[i], bfr[j], acc[i][j], 0, 0, 0);
    }

    const int r4 = (lane >> 4) * 4;
    const int cn = lane & 15;
#pragma unroll
    for (int i = 0; i < 4; ++i) {
#pragma unroll
        for (int j = 0; j < 4; ++j) {
            int row0 = bm + waveM + i * 16 + r4;
            int col  = bn + waveN + j * 16 + cn;
            float bc = (MODE == 2) ? (blockIdx.z == 0 ? bias[col] : 0.0f) : bias[col];
#pragma unroll
            for (int r = 0; r < 4; ++r) {
                float val = acc[i][j][r] + bc;
                if (MODE == 0) {
                    C[(size_t)(row0 + r) * N + col] = val;
                } else if (MODE == 2) {
                    atomicAdd(&C[(size_t)(row0 + r) * N + col], val);
                } else {
                    int row = row0 + r;
                    int b = row >> 11;          // row = b*2048 + s
                    int s = row & 2047;
                    int d = col & 127;
                    u16 o = f2bf(val);
                    if (col < 2048) {
                        int h = col >> 7;
                        qb[(((size_t)(b * 16 + h) * SEQ) + s) * 128 + d] = o;
                    } else if (col < 2560) {
                        int h = (col - 2048) >> 7;
                        kb[(((size_t)(b * 4 + h) * SEQ) + s) * 128 + d] = o;
                    } else {
                        int h = (col - 2560) >> 7;
                        vt[(((size_t)(b * 4 + h) * 128) + d) * SEQ + s] = o;  // V^T
                    }
                }
            }
        }
    }
}

// ---------------------------------------------------------------- RoPE in-place on k only
__global__ void rope_k(u16* __restrict__ kb,
                       const float* __restrict__ cosb, const float* __restrict__ sinb)
{
    const int n = 16384 * 64;          // B*4*SEQ rows x 64 pair-lanes
    int i = blockIdx.x * blockDim.x + threadIdx.x;
    if (i >= n) return;
    int d0  = i & 63;
    int row = i >> 6;
    u16* base = kb + (size_t)row * 128;
    int s = row & (SEQ - 1);
    float c  = cosb[s * 128 + d0];
    float sn = sinb[s * 128 + d0];
    float a0 = bf2f(base[d0]);
    float a1 = bf2f(base[d0 + 64]);
    base[d0]      = f2bf(a0 * c - a1 * sn);
    base[d0 + 64] = f2bf(a1 * c + a0 * sn);
}

// ---------------------------------------------------------------- MFMA flash attention v10
// = wave->tile specialization, dbuf 64-col tiles, XCD slice swizzle, fused Q-rope,
//   complementary-pair co-residency balance (r12, +3us).
__global__ __launch_bounds__(256, 2) void attn_mfma(
    const u16* __restrict__ qb, const u16* __restrict__ kb,
    const u16* __restrict__ vt, u16* __restrict__ ob,
    const float* __restrict__ cosb, const float* __restrict__ sinb)
{
    __shared__ __align__(16) u16 Ks[2][4][64][32];    // 2x16KB: [buf][d-chunk][kcol][32]
    __shared__ __align__(16) u16 Vts[2][2][128][32];  // 2x16KB: [buf][kcol-chunk][d][32]
    __shared__ __align__(16) u16 Ph[4][16][64];       // 8KB: per-wave rot-swizzled P

    const int id   = blockIdx.x;
    const int s8   = id & 7;
    const int n    = id >> 3;          // 0..63
    const int h_lo = n >> 4;           // 0..3
    int pair = n & 15;
    if (h_lo >= 2) pair ^= 15;         // complementary-pair balance (r12)
    const int b    = s8 >> 2;
    const int kvh  = s8 & 3;
    const int h    = kvh * 4 + h_lo;
    const int qA   = pair, qB = 31 - pair;

    const int tid  = threadIdx.x;
    const int lane = tid & 63;
    const int w    = tid >> 6;
    const int c16  = lane & 15;
    const int quad = lane >> 4;
    const int T    = w >> 1;           // 0: tile A, 1: tile B
    const int sub  = w & 1;            // 32-row half within the tile
    const int qT   = T ? qB : qA;
    const float qscale = 0.08838834764831845f * 1.4426950408889634f; // 1/sqrt(128)*log2(e)

    const u16* kbase  = kb + ((size_t)(b * 4 + kvh) * SEQ) * 128;
    const u16* vtbase = vt + ((size_t)(b * 4 + kvh) * 128) * SEQ;

    // Q A-frags in registers: raw load -> RoPE (f32) -> scale -> bf16
    bf16x8 qf[2][4];
#pragma unroll
    for (int s = 0; s < 2; ++s) {
        const int spos = qT * 64 + sub * 32 + s * 16 + c16;   // seq position 0..2047
        const u16* qp = qb + (((size_t)(b * 16 + h)) * SEQ + spos) * 128;
        bf16x8 t[4];
#pragma unroll
        for (int kk = 0; kk < 4; ++kk)
            t[kk] = *(const bf16x8*)(qp + kk * 32 + quad * 8);
#pragma unroll
        for (int kk = 0; kk < 2; ++kk) {
            const float* cp = cosb + (size_t)spos * 128 + kk * 32 + quad * 8;
            const float* sp = sinb + (size_t)spos * 128 + kk * 32 + quad * 8;
#pragma unroll
            for (int e = 0; e < 8; ++e) {
                float a0 = (float)t[kk][e];
                float a1 = (float)t[kk + 2][e];
                float c  = cp[e];
                float sn = sp[e];
                qf[s][kk][e]     = (__bf16)((a0 * c - a1 * sn) * qscale);
                qf[s][kk + 2][e] = (__bf16)((a1 * c + a0 * sn) * qscale);
            }
        }
    }

    int ksrc[4], vsrc[4];
#pragma unroll
    for (int it = 0; it < 4; ++it) {
        int o  = (it * 4 + w) * 1024 + lane * 16;   // physical byte offset in 16KB tile
        int kk = o >> 12;                            // K panel (d-chunk) 0..3
        int r  = (o >> 6) & 63;                      // kcol
        int c  = (o >> 4) & 3;                       // 16B chunk in row
        ksrc[it] = r * 128 + kk * 32 + c * 8;
        int p2 = o >> 13;                            // V panel (kcol-chunk) 0..1
        int d  = (o >> 6) & 127;                     // d
        vsrc[it] = d * SEQ + p2 * 32 + c * 8;
    }

    const int nB = qB + 1;
    const int rowL0 = qT * 64 + sub * 32 + quad * 4;

    f32x4 o[2][8] = {};
    float l[2][4] = {};

    u16* KsF  = &Ks[0][0][0][0];
    u16* VtsF = &Vts[0][0][0][0];

#pragma unroll
    for (int it = 0; it < 4; ++it) {
        gl_lds16(kbase  + ksrc[it], KsF  + (it * 4 + w) * 512);
        gl_lds16(vtbase + vsrc[it], VtsF + (it * 4 + w) * 512);
    }
    __syncthreads();

    for (int kt = 0; kt < nB; ++kt) {
        const int cur = kt & 1;

        if (kt + 1 < nB) {
            const u16* kg = kbase  + (size_t)(kt + 1) * (64 * 128);
            const u16* vg = vtbase + (kt + 1) * 64;
            u16* kd = KsF  + ((kt + 1) & 1) * (4 * 64 * 32);
            u16* vd = VtsF + ((kt + 1) & 1) * (2 * 128 * 32);
#pragma unroll
            for (int it = 0; it < 4; ++it) {
                gl_lds16(kg + ksrc[it], kd + (it * 4 + w) * 512);
                gl_lds16(vg + vsrc[it], vd + (it * 4 + w) * 512);
            }
        }

        if (T == 1 || kt <= qA) {
            f32x4 sS[2][4] = {};
#pragma unroll
            for (int kk = 0; kk < 4; ++kk)
#pragma unroll
                for (int j = 0; j < 4; ++j) {
                    bf16x8 kf = *(const bf16x8*)&Ks[cur][kk][j * 16 + c16][quad * 8];
                    sS[0][j] = __builtin_amdgcn_mfma_f32_16x16x32_bf16(qf[0][kk], kf, sS[0][j], 0, 0, 0);
                    sS[1][j] = __builtin_amdgcn_mfma_f32_16x16x32_bf16(qf[1][kk], kf, sS[1][j], 0, 0, 0);
                }

            if (kt == qT) {
#pragma unroll
                for (int s = 0; s < 2; ++s)
#pragma unroll
                    for (int j = 0; j < 4; ++j)
#pragma unroll
                        for (int rr = 0; rr < 4; ++rr)
                            if (kt * 64 + j * 16 + c16 > rowL0 + s * 16 + rr) sS[s][j][rr] = -1e30f;
            }

            bf16x8 pa[2][2];
#pragma unroll
            for (int s = 0; s < 2; ++s) {
#pragma unroll
                for (int jj = 0; jj < 4; ++jj)
#pragma unroll
                    for (int rr = 0; rr < 4; ++rr) {
                        float p = __builtin_amdgcn_exp2f(sS[s][jj][rr]);
                        l[s][rr] += p;
                        int row = quad * 4 + rr;
                        *(__bf16*)&Ph[w][row][(((jj * 2 + (c16 >> 3)) + row) & 7) * 8 + (c16 & 7)] = (__bf16)p;
                    }
#pragma unroll
                for (int k2 = 0; k2 < 2; ++k2)
                    pa[s][k2] = *(const bf16x8*)&Ph[w][c16][(((k2 * 4 + quad) + c16) & 7) * 8];
            }

#pragma unroll
            for (int k2 = 0; k2 < 2; ++k2)
#pragma unroll
                for (int nt = 0; nt < 8; ++nt) {
                    bf16x8 vf = *(const bf16x8*)&Vts[cur][k2][nt * 16 + c16][quad * 8];
                    o[0][nt] = __builtin_amdgcn_mfma_f32_16x16x32_bf16(pa[0][k2], vf, o[0][nt], 0, 0, 0);
                    o[1][nt] = __builtin_amdgcn_mfma_f32_16x16x32_bf16(pa[1][k2], vf, o[1][nt], 0, 0, 0);
                }
        }

        __syncthreads();
    }

#pragma unroll
    for (int s = 0; s < 2; ++s) {
        float li[4];
#pragma unroll
        for (int rr = 0; rr < 4; ++rr) {
            float la = l[s][rr];
            la += __shfl_xor(la, 1);
            la += __shfl_xor(la, 2);
            la += __shfl_xor(la, 4);
            la += __shfl_xor(la, 8);
            li[rr] = 1.0f / la;
        }
        const size_t rowG = (size_t)b * SEQ + rowL0 + s * 16;
#pragma unroll
        for (int nt = 0; nt < 8; ++nt)
#pragma unroll
            for (int rr = 0; rr < 4; ++rr)
                ob[(rowG + rr) * 2048 + h * 128 + nt * 16 + c16] = f2bf(o[s][nt][rr] * li[rr]);
    }
}

// ---------------------------------------------------------------- launch
extern "C" void kernel_launch(void* const* d_in, const int* in_sizes, int n_in,
                              void* d_out, int out_size, void* d_ws, size_t ws_size,
                              hipStream_t stream) {
    const float* x    = (const float*)d_in[0];
    const float* wq   = (const float*)d_in[1];
    const float* bq   = (const float*)d_in[2];
    const float* wk   = (const float*)d_in[3];
    const float* bk   = (const float*)d_in[4];
    const float* wv   = (const float*)d_in[5];
    const float* bv   = (const float*)d_in[6];
    const float* wo   = (const float*)d_in[7];
    const float* bo   = (const float*)d_in[8];
    const float* cosb = (const float*)d_in[9];
    const float* sinb = (const float*)d_in[10];
    float* out = (float*)d_out;

    char* ws = (char*)d_ws;
    const size_t OFF_WQKV = 0;              // 12,582,912  packed [wq|wk|wv] bf16
    const size_t OFF_BIAS = 12582912;       //     16,384  packed qkv bias f32
    const size_t OFF_QB   = 12599296;       // 16,777,216  q bf16 (B,16,S,128)
    const size_t OFF_KB   = 29376512;       //  4,194,304  k bf16 (B,4,S,128)
    const size_t OFF_VT   = 33570816;       //  4,194,304  v^T bf16 (B,4,128,S)
    const size_t OFF_XB   = 37765120;       // 16,777,216  x bf16; later attn out bf16
    const size_t OFF_WOB  = 54542336;       //  8,388,608  wo bf16 (fused-prep path)
    const bool bigws = ws_size >= (OFF_WOB + 8388608);

    u16*   wqkvb = (u16*)(ws + OFF_WQKV);
    float* biasb = (float*)(ws + OFF_BIAS);
    u16*   qb2   = (u16*)(ws + OFF_QB);
    u16*   kb2   = (u16*)(ws + OFF_KB);
    u16*   vt2   = (u16*)(ws + OFF_VT);
    u16*   xb    = (u16*)(ws + OFF_XB);
    u16*   attnb = (u16*)(ws + OFF_XB);     // reuse after GEMM1
    u16*   wob   = bigws ? (u16*)(ws + OFF_WOB)
                         : (u16*)(ws + OFF_WQKV);   // fallback: reuse after GEMM1

    // 0. zero d_out for gemm2's split-K atomic accumulation (stream-ordered,
    //    graph-capture legal; re-executed every replay so self-contained)
    hipMemsetAsync(out, 0, (size_t)4096 * 2048 * 4, stream);

    // 1. fused prep: x->bf16, wq/wk/wv->bf16 packed, bias pack (+ wo->bf16 if bigws)
    prep<<<4096, 256, 0, stream>>>(x, wq, wk, wv, wo, bq, bk, bv,
                                   xb, wqkvb, biasb, bigws ? wob : nullptr);

    // 2. qkv = x @ [wq|wk|wv]^T + bias (proven 128^2 BK32 kernel, natural grid)
    gemm_bt<1><<<dim3(32, 24), 256, 0, stream>>>(xb, wqkvb, biasb, nullptr,
                                                 qb2, kb2, vt2, 4096, 3072, 2048);

    // 3. (fallback only) wo -> bf16 into wqkv region after gemm1
    if (!bigws) cvt_f32_bf16<<<4096, 256, 0, stream>>>(wo, wob, 1048576);

    // 4. RoPE in-place on k only (q rope fused into attn)
    rope_k<<<4096, 256, 0, stream>>>(kb2, cosb, sinb);

    // 5. causal GQA MFMA attention v10 -> (B*S, 2048) bf16
    attn_mfma<<<512, 256, 0, stream>>>(qb2, kb2, vt2, attnb, cosb, sinb);

    // 6. out += attn @ wo^T (+bo on bz==0): split-K=2, 1024 blocks = 4/CU
    gemm_bt<2><<<dim3(32, 16, 2), 256, 0, stream>>>(attnb, wob, bo, out,
                                                    nullptr, nullptr, nullptr, 4096, 2048, 2048);
}

// Round 14
// 329.277 us; speedup vs baseline: 1.1713x; 1.1713x over previous
//
#include <hip/hip_runtime.h>

typedef unsigned short u16;
typedef __bf16 bf16x8 __attribute__((ext_vector_type(8)));
typedef float  f32x4  __attribute__((ext_vector_type(4)));

#define SEQ 2048

__device__ __forceinline__ float bf2f(u16 u) {
    union { unsigned int i; float f; } c;
    c.i = ((unsigned int)u) << 16;
    return c.f;
}
__device__ __forceinline__ u16 f2bf(float f) {
    union { float f; unsigned int i; } c;
    c.f = f;
    unsigned int u = c.i;
    u += 0x7FFFu + ((u >> 16) & 1u);   // round-to-nearest-even
    return (u16)(u >> 16);
}

// async global->LDS, 16B per lane; lds dest = wave-uniform base + lane*16
__device__ __forceinline__ void gl_lds16(const u16* g, u16* l) {
    __builtin_amdgcn_global_load_lds(
        (const __attribute__((address_space(1))) unsigned int*)(g),
        (__attribute__((address_space(3))) unsigned int*)(l), 16, 0, 0);
}

__device__ __forceinline__ void cvt4(const float* s, u16* d) {
    float4 v = *(const float4*)s;
    ushort4 o;
    o.x = f2bf(v.x); o.y = f2bf(v.y); o.z = f2bf(v.z); o.w = f2bf(v.w);
    *(ushort4*)d = o;
}

// ---------------------------------------------------------------- fused prep
// Converts x/wq/wk/wv (+ wo when wob != nullptr) to bf16 and packs biases.
// Fused-wo path removes the separate cvt launch (~6us, confirmed r10/r11).
__global__ void prep(const float* __restrict__ x,
                     const float* __restrict__ wq, const float* __restrict__ wk,
                     const float* __restrict__ wv, const float* __restrict__ wo,
                     const float* __restrict__ bq, const float* __restrict__ bk,
                     const float* __restrict__ bv,
                     u16* __restrict__ xb, u16* __restrict__ wqkvb,
                     float* __restrict__ biasb, u16* __restrict__ wob)
{
    const int E0 = 2097152;            // x float4s
    const int E1 = E0 + 1048576;       // wq
    const int E2 = E1 + 262144;        // wk
    const int E3 = E2 + 262144;        // wv
    const int E4 = E3 + 768;           // bias float4s
    const int EN = wob ? (E4 + 1048576) : E4;   // + wo float4s (fused path)
    int i = blockIdx.x * blockDim.x + threadIdx.x;
    int stride = gridDim.x * blockDim.x;
    for (; i < EN; i += stride) {
        if (i < E0)      cvt4(x  + (size_t)i * 4,        xb    + (size_t)i * 4);
        else if (i < E1) cvt4(wq + (size_t)(i - E0) * 4, wqkvb + (size_t)(i - E0) * 4);
        else if (i < E2) cvt4(wk + (size_t)(i - E1) * 4, wqkvb + 4194304 + (size_t)(i - E1) * 4);
        else if (i < E3) cvt4(wv + (size_t)(i - E2) * 4, wqkvb + 5242880 + (size_t)(i - E2) * 4);
        else if (i < E4) {
            int j = i - E3;            // 0..767
            const float* src = (j < 512) ? (bq + j * 4)
                             : (j < 640) ? (bk + (j - 512) * 4)
                                         : (bv + (j - 640) * 4);
            *(float4*)&biasb[j * 4] = *(const float4*)src;
        } else {
            int j = i - E4;            // 0..1048575
            cvt4(wo + (size_t)j * 4, wob + (size_t)j * 4);
        }
    }
}

__global__ void cvt_f32_bf16(const float* __restrict__ in, u16* __restrict__ out, int n4) {
    int i = blockIdx.x * blockDim.x + threadIdx.x;
    int stride = gridDim.x * blockDim.x;
    for (; i < n4; i += stride) cvt4(in + (size_t)i * 4, out + (size_t)i * 4);
}

// ---------------------------------------------------------------- GEMM C = A*B^T + bias (128^2, BK=32, m97 pattern)
// PROVEN kernel for both gemms. Natural dim3 grid.
// Structural ledger (do not revisit without new evidence):
//  - r7: 256^2 deep-pipeline starves grid (192 blocks < 256 CUs) -> -16%
//  - r8: manual XCD remap destroys default A-panel L2 locality -> -18%
//  - r10: T2 swizzle + BK=64 null-to-negative on 2-barrier structure -> -19%
//  - r13: split-K=2 fp32 atomics double WRITE_SIZE, occupancy flat -> -28%
template<int MODE>
__global__ __launch_bounds__(256) void gemm_bt(
    const u16* __restrict__ A, const u16* __restrict__ B,
    const float* __restrict__ bias, float* __restrict__ C,
    u16* __restrict__ qb, u16* __restrict__ kb, u16* __restrict__ vt,
    int M, int N, int K)
{
    __shared__ __align__(16) u16 lA[128 * 32];
    __shared__ __align__(16) u16 lB[128 * 32];
    const int tid   = threadIdx.x;
    const int lane  = tid & 63;
    const int wave  = tid >> 6;
    const int waveM = (wave >> 1) * 64;
    const int waveN = (wave & 1) * 64;
    const int bm = blockIdx.x * 128;
    const int bn = blockIdx.y * 128;
    const int lrow = lane & 15;
    const int koff = (lane >> 4) * 8;

    f32x4 acc[4][4] = {};

    for (int k0 = 0; k0 < K; k0 += 32) {
        __syncthreads();
#pragma unroll
        for (int p = 0; p < 2; ++p) {
            int idx = p * 256 + tid;    // 0..511
            int row = idx >> 2;         // 0..127
            int ch  = idx & 3;          // 16B chunk
            gl_lds16(&A[(size_t)(bm + row) * K + k0 + ch * 8], &lA[(p * 256 + wave * 64) * 8]);
            gl_lds16(&B[(size_t)(bn + row) * K + k0 + ch * 8], &lB[(p * 256 + wave * 64) * 8]);
        }
        __syncthreads();

        bf16x8 af[4], bfr[4];
#pragma unroll
        for (int i = 0; i < 4; ++i)
            af[i] = *(const bf16x8*)&lA[(waveM + i * 16 + lrow) * 32 + koff];
#pragma unroll
        for (int j = 0; j < 4; ++j)
            bfr[j] = *(const bf16x8*)&lB[(waveN + j * 16 + lrow) * 32 + koff];
#pragma unroll
        for (int i = 0; i < 4; ++i)
#pragma unroll
            for (int j = 0; j < 4; ++j)
                acc[i][j] = __builtin_amdgcn_mfma_f32_16x16x32_bf16(
                    af[i], bfr[j], acc[i][j], 0, 0, 0);
    }

    const int r4 = (lane >> 4) * 4;
    const int cn = lane & 15;
#pragma unroll
    for (int i = 0; i < 4; ++i) {
#pragma unroll
        for (int j = 0; j < 4; ++j) {
            int row0 = bm + waveM + i * 16 + r4;
            int col  = bn + waveN + j * 16 + cn;
            float bc = bias[col];
#pragma unroll
            for (int r = 0; r < 4; ++r) {
                float val = acc[i][j][r] + bc;
                if (MODE == 0) {
                    C[(size_t)(row0 + r) * N + col] = val;
                } else {
                    int row = row0 + r;
                    int b = row >> 11;          // row = b*2048 + s
                    int s = row & 2047;
                    int d = col & 127;
                    u16 o = f2bf(val);
                    if (col < 2048) {
                        int h = col >> 7;
                        qb[(((size_t)(b * 16 + h) * SEQ) + s) * 128 + d] = o;
                    } else if (col < 2560) {
                        int h = (col - 2048) >> 7;
                        kb[(((size_t)(b * 4 + h) * SEQ) + s) * 128 + d] = o;
                    } else {
                        int h = (col - 2560) >> 7;
                        vt[(((size_t)(b * 4 + h) * 128) + d) * SEQ + s] = o;  // V^T
                    }
                }
            }
        }
    }
}

// ---------------------------------------------------------------- RoPE in-place on k only
// (q rope is fused into attn's Q-frag load; cos[s,d] == cos[s,d+64] in this rope)
__global__ void rope_k(u16* __restrict__ kb,
                       const float* __restrict__ cosb, const float* __restrict__ sinb)
{
    const int n = 16384 * 64;          // B*4*SEQ rows x 64 pair-lanes
    int i = blockIdx.x * blockDim.x + threadIdx.x;
    if (i >= n) return;
    int d0  = i & 63;
    int row = i >> 6;
    u16* base = kb + (size_t)row * 128;
    int s = row & (SEQ - 1);
    float c  = cosb[s * 128 + d0];
    float sn = sinb[s * 128 + d0];
    float a0 = bf2f(base[d0]);
    float a1 = bf2f(base[d0 + 64]);
    base[d0]      = f2bf(a0 * c - a1 * sn);
    base[d0 + 64] = f2bf(a1 * c + a0 * sn);
}

// ---------------------------------------------------------------- MFMA flash attention v10
// = wave->tile specialization, dbuf 64-col tiles, XCD slice swizzle, fused Q-rope,
//   complementary-pair co-residency balance (r12, +3us).
__global__ __launch_bounds__(256, 2) void attn_mfma(
    const u16* __restrict__ qb, const u16* __restrict__ kb,
    const u16* __restrict__ vt, u16* __restrict__ ob,
    const float* __restrict__ cosb, const float* __restrict__ sinb)
{
    __shared__ __align__(16) u16 Ks[2][4][64][32];    // 2x16KB: [buf][d-chunk][kcol][32]
    __shared__ __align__(16) u16 Vts[2][2][128][32];  // 2x16KB: [buf][kcol-chunk][d][32]
    __shared__ __align__(16) u16 Ph[4][16][64];       // 8KB: per-wave rot-swizzled P

    const int id   = blockIdx.x;
    const int s8   = id & 7;
    const int n    = id >> 3;          // 0..63
    const int h_lo = n >> 4;           // 0..3
    int pair = n & 15;
    if (h_lo >= 2) pair ^= 15;         // complementary-pair balance (r12)
    const int b    = s8 >> 2;
    const int kvh  = s8 & 3;
    const int h    = kvh * 4 + h_lo;
    const int qA   = pair, qB = 31 - pair;

    const int tid  = threadIdx.x;
    const int lane = tid & 63;
    const int w    = tid >> 6;
    const int c16  = lane & 15;
    const int quad = lane >> 4;
    const int T    = w >> 1;           // 0: tile A, 1: tile B
    const int sub  = w & 1;            // 32-row half within the tile
    const int qT   = T ? qB : qA;
    const float qscale = 0.08838834764831845f * 1.4426950408889634f; // 1/sqrt(128)*log2(e)

    const u16* kbase  = kb + ((size_t)(b * 4 + kvh) * SEQ) * 128;
    const u16* vtbase = vt + ((size_t)(b * 4 + kvh) * 128) * SEQ;

    // Q A-frags in registers: raw load -> RoPE (f32) -> scale -> bf16
    bf16x8 qf[2][4];
#pragma unroll
    for (int s = 0; s < 2; ++s) {
        const int spos = qT * 64 + sub * 32 + s * 16 + c16;   // seq position 0..2047
        const u16* qp = qb + (((size_t)(b * 16 + h)) * SEQ + spos) * 128;
        bf16x8 t[4];
#pragma unroll
        for (int kk = 0; kk < 4; ++kk)
            t[kk] = *(const bf16x8*)(qp + kk * 32 + quad * 8);
#pragma unroll
        for (int kk = 0; kk < 2; ++kk) {
            const float* cp = cosb + (size_t)spos * 128 + kk * 32 + quad * 8;
            const float* sp = sinb + (size_t)spos * 128 + kk * 32 + quad * 8;
#pragma unroll
            for (int e = 0; e < 8; ++e) {
                float a0 = (float)t[kk][e];
                float a1 = (float)t[kk + 2][e];
                float c  = cp[e];
                float sn = sp[e];
                qf[s][kk][e]     = (__bf16)((a0 * c - a1 * sn) * qscale);
                qf[s][kk + 2][e] = (__bf16)((a1 * c + a0 * sn) * qscale);
            }
        }
    }

    int ksrc[4], vsrc[4];
#pragma unroll
    for (int it = 0; it < 4; ++it) {
        int o  = (it * 4 + w) * 1024 + lane * 16;   // physical byte offset in 16KB tile
        int kk = o >> 12;                            // K panel (d-chunk) 0..3
        int r  = (o >> 6) & 63;                      // kcol
        int c  = (o >> 4) & 3;                       // 16B chunk in row
        ksrc[it] = r * 128 + kk * 32 + c * 8;
        int p2 = o >> 13;                            // V panel (kcol-chunk) 0..1
        int d  = (o >> 6) & 127;                     // d
        vsrc[it] = d * SEQ + p2 * 32 + c * 8;
    }

    const int nB = qB + 1;
    const int rowL0 = qT * 64 + sub * 32 + quad * 4;

    f32x4 o[2][8] = {};
    float l[2][4] = {};

    u16* KsF  = &Ks[0][0][0][0];
    u16* VtsF = &Vts[0][0][0][0];

#pragma unroll
    for (int it = 0; it < 4; ++it) {
        gl_lds16(kbase  + ksrc[it], KsF  + (it * 4 + w) * 512);
        gl_lds16(vtbase + vsrc[it], VtsF + (it * 4 + w) * 512);
    }
    __syncthreads();

    for (int kt = 0; kt < nB; ++kt) {
        const int cur = kt & 1;

        if (kt + 1 < nB) {
            const u16* kg = kbase  + (size_t)(kt + 1) * (64 * 128);
            const u16* vg = vtbase + (kt + 1) * 64;
            u16* kd = KsF  + ((kt + 1) & 1) * (4 * 64 * 32);
            u16* vd = VtsF + ((kt + 1) & 1) * (2 * 128 * 32);
#pragma unroll
            for (int it = 0; it < 4; ++it) {
                gl_lds16(kg + ksrc[it], kd + (it * 4 + w) * 512);
                gl_lds16(vg + vsrc[it], vd + (it * 4 + w) * 512);
            }
        }

        if (T == 1 || kt <= qA) {
            f32x4 sS[2][4] = {};
#pragma unroll
            for (int kk = 0; kk < 4; ++kk)
#pragma unroll
                for (int j = 0; j < 4; ++j) {
                    bf16x8 kf = *(const bf16x8*)&Ks[cur][kk][j * 16 + c16][quad * 8];
                    sS[0][j] = __builtin_amdgcn_mfma_f32_16x16x32_bf16(qf[0][kk], kf, sS[0][j], 0, 0, 0);
                    sS[1][j] = __builtin_amdgcn_mfma_f32_16x16x32_bf16(qf[1][kk], kf, sS[1][j], 0, 0, 0);
                }

            if (kt == qT) {
#pragma unroll
                for (int s = 0; s < 2; ++s)
#pragma unroll
                    for (int j = 0; j < 4; ++j)
#pragma unroll
                        for (int rr = 0; rr < 4; ++rr)
                            if (kt * 64 + j * 16 + c16 > rowL0 + s * 16 + rr) sS[s][j][rr] = -1e30f;
            }

            bf16x8 pa[2][2];
#pragma unroll
            for (int s = 0; s < 2; ++s) {
#pragma unroll
                for (int jj = 0; jj < 4; ++jj)
#pragma unroll
                    for (int rr = 0; rr < 4; ++rr) {
                        float p = __builtin_amdgcn_exp2f(sS[s][jj][rr]);
                        l[s][rr] += p;
                        int row = quad * 4 + rr;
                        *(__bf16*)&Ph[w][row][(((jj * 2 + (c16 >> 3)) + row) & 7) * 8 + (c16 & 7)] = (__bf16)p;
                    }
#pragma unroll
                for (int k2 = 0; k2 < 2; ++k2)
                    pa[s][k2] = *(const bf16x8*)&Ph[w][c16][(((k2 * 4 + quad) + c16) & 7) * 8];
            }

#pragma unroll
            for (int k2 = 0; k2 < 2; ++k2)
#pragma unroll
                for (int nt = 0; nt < 8; ++nt) {
                    bf16x8 vf = *(const bf16x8*)&Vts[cur][k2][nt * 16 + c16][quad * 8];
                    o[0][nt] = __builtin_amdgcn_mfma_f32_16x16x32_bf16(pa[0][k2], vf, o[0][nt], 0, 0, 0);
                    o[1][nt] = __builtin_amdgcn_mfma_f32_16x16x32_bf16(pa[1][k2], vf, o[1][nt], 0, 0, 0);
                }
        }

        __syncthreads();
    }

#pragma unroll
    for (int s = 0; s < 2; ++s) {
        float li[4];
#pragma unroll
        for (int rr = 0; rr < 4; ++rr) {
            float la = l[s][rr];
            la += __shfl_xor(la, 1);
            la += __shfl_xor(la, 2);
            la += __shfl_xor(la, 4);
            la += __shfl_xor(la, 8);
            li[rr] = 1.0f / la;
        }
        const size_t rowG = (size_t)b * SEQ + rowL0 + s * 16;
#pragma unroll
        for (int nt = 0; nt < 8; ++nt)
#pragma unroll
            for (int rr = 0; rr < 4; ++rr)
                ob[(rowG + rr) * 2048 + h * 128 + nt * 16 + c16] = f2bf(o[s][nt][rr] * li[rr]);
    }
}

// ---------------------------------------------------------------- launch
extern "C" void kernel_launch(void* const* d_in, const int* in_sizes, int n_in,
                              void* d_out, int out_size, void* d_ws, size_t ws_size,
                              hipStream_t stream) {
    const float* x    = (const float*)d_in[0];
    const float* wq   = (const float*)d_in[1];
    const float* bq   = (const float*)d_in[2];
    const float* wk   = (const float*)d_in[3];
    const float* bk   = (const float*)d_in[4];
    const float* wv   = (const float*)d_in[5];
    const float* bv   = (const float*)d_in[6];
    const float* wo   = (const float*)d_in[7];
    const float* bo   = (const float*)d_in[8];
    const float* cosb = (const float*)d_in[9];
    const float* sinb = (const float*)d_in[10];
    float* out = (float*)d_out;

    char* ws = (char*)d_ws;
    const size_t OFF_WQKV = 0;              // 12,582,912  packed [wq|wk|wv] bf16
    const size_t OFF_BIAS = 12582912;       //     16,384  packed qkv bias f32
    const size_t OFF_QB   = 12599296;       // 16,777,216  q bf16 (B,16,S,128)
    const size_t OFF_KB   = 29376512;       //  4,194,304  k bf16 (B,4,S,128)
    const size_t OFF_VT   = 33570816;       //  4,194,304  v^T bf16 (B,4,128,S)
    const size_t OFF_XB   = 37765120;       // 16,777,216  x bf16; later attn out bf16
    const size_t OFF_WOB  = 54542336;       //  8,388,608  wo bf16 (fused-prep path)
    const bool bigws = ws_size >= (OFF_WOB + 8388608);

    u16*   wqkvb = (u16*)(ws + OFF_WQKV);
    float* biasb = (float*)(ws + OFF_BIAS);
    u16*   qb2   = (u16*)(ws + OFF_QB);
    u16*   kb2   = (u16*)(ws + OFF_KB);
    u16*   vt2   = (u16*)(ws + OFF_VT);
    u16*   xb    = (u16*)(ws + OFF_XB);
    u16*   attnb = (u16*)(ws + OFF_XB);     // reuse after GEMM1
    u16*   wob   = bigws ? (u16*)(ws + OFF_WOB)
                         : (u16*)(ws + OFF_WQKV);   // fallback: reuse after GEMM1

    // 1. fused prep: x->bf16, wq/wk/wv->bf16 packed, bias pack (+ wo->bf16 if bigws)
    prep<<<4096, 256, 0, stream>>>(x, wq, wk, wv, wo, bq, bk, bv,
                                   xb, wqkvb, biasb, bigws ? wob : nullptr);

    // 2. qkv = x @ [wq|wk|wv]^T + bias (proven 128^2 BK32 kernel, natural grid)
    gemm_bt<1><<<dim3(32, 24), 256, 0, stream>>>(xb, wqkvb, biasb, nullptr,
                                                 qb2, kb2, vt2, 4096, 3072, 2048);

    // 3. (fallback only) wo -> bf16 into wqkv region after gemm1
    if (!bigws) cvt_f32_bf16<<<4096, 256, 0, stream>>>(wo, wob, 1048576);

    // 4. RoPE in-place on k only (q rope fused into attn)
    rope_k<<<4096, 256, 0, stream>>>(kb2, cosb, sinb);

    // 5. causal GQA MFMA attention v10 (complementary-pair balance) -> (B*S, 2048) bf16
    attn_mfma<<<512, 256, 0, stream>>>(qb2, kb2, vt2, attnb, cosb, sinb);

    // 6. out = attn @ wo^T + bo  (fp32 to d_out; proven kernel, natural grid)
    gemm_bt<0><<<dim3(32, 16), 256, 0, stream>>>(attnb, wob, bo, out,
                                                 nullptr, nullptr, nullptr, 4096, 2048, 2048);
}